// Round 6
// baseline (189.603 us; speedup 1.0000x reference)
//
#include <hip/hip_runtime.h>
#include <hip/hip_bf16.h>

typedef __hip_bfloat16 bf16;
using bf16x8 = __attribute__((ext_vector_type(8))) short;
using f32x4  = __attribute__((ext_vector_type(4))) float;

#define C_DIM 512
#define L_DIM 2048
#define B_DIM 8

#define MFMA16(a, b, c) __builtin_amdgcn_mfma_f32_16x16x32_bf16(a, b, c, 0, 0, 0)
#define SGB __builtin_amdgcn_sched_group_barrier

// ---- workspace layout (bytes) ----
static const size_t OFF_XT  = 0;                      // 16 MB
static const size_t OFF_WQB = 16777216;
static const size_t OFF_WKB = 16842752;
static const size_t OFF_WVB = 16908288;
static const size_t OFF_WOB = 17432576;
static const size_t OFF_QT  = 17956864;
static const size_t OFF_KT  = 20054016;
static const size_t OFF_VT  = 22151168;
static const size_t OFF_O1  = 38928384;

// ---------------- K0a: weights fp32 -> bf16 ----------------
__global__ void k_wcvt(const float* __restrict__ Wq, const float* __restrict__ Wk,
                       const float* __restrict__ Wv, const float* __restrict__ Wo,
                       bf16* __restrict__ Wqb, bf16* __restrict__ Wkb,
                       bf16* __restrict__ Wvb, bf16* __restrict__ Wob) {
    int i = blockIdx.x * 256 + threadIdx.x;
    if (i < 32768)        Wqb[i]          = __float2bfloat16(Wq[i]);
    else if (i < 65536)   Wkb[i - 32768]  = __float2bfloat16(Wk[i - 32768]);
    else if (i < 327680)  Wvb[i - 65536]  = __float2bfloat16(Wv[i - 65536]);
    else                  Wob[i - 327680] = __float2bfloat16(Wo[i - 327680]);
}

// ---------------- K0b: transpose x [B][C][L] fp32 -> xT [B][L][C] bf16 ----------------
// Round-6: write phase vectorized to bf16x2 (was scalar 2B stores -- G13).
__global__ __launch_bounds__(256) void k_tr(const float* __restrict__ x,
                                            bf16* __restrict__ xT) {
    __shared__ float T[64][65];
    const int b = blockIdx.z;
    const int l0 = blockIdx.x * 64, c0 = blockIdx.y * 64;
    const int tx = threadIdx.x & 63, ty = threadIdx.x >> 6;

    const float* xp = x + ((size_t)b * C_DIM + c0) * L_DIM + l0;
#pragma unroll
    for (int i = 0; i < 16; ++i) {
        int c = i * 4 + ty;
        T[c][tx] = xp[(size_t)c * L_DIM + tx];
    }
    __syncthreads();
    const int c2 = (threadIdx.x & 31) * 2;
    const int lr = threadIdx.x >> 5;     // 0..7
#pragma unroll
    for (int i = 0; i < 8; ++i) {
        int l = i * 8 + lr;
        __hip_bfloat162 u = __float22bfloat162_rn(make_float2(T[c2][l], T[c2 + 1][l]));
        *reinterpret_cast<__hip_bfloat162*>(
            &xT[((size_t)b * L_DIM + l0 + l) * C_DIM + c0 + c2]) = u;
    }
}

// ---------------- K1: QKV projection via MFMA (reg-prefetched K-loop) ----------------
// Q output pre-scaled by 0.125*log2(e) so k_attn computes P = exp2(s') directly
// (drops the per-element v_mul by log2e in the attention hot loop).
__global__ __launch_bounds__(256, 2) void k_qkv(const bf16* __restrict__ xT,
                                                const bf16* __restrict__ Wqb, const float* __restrict__ bq,
                                                const bf16* __restrict__ Wkb, const float* __restrict__ bk,
                                                const bf16* __restrict__ Wvb, const float* __restrict__ bv,
                                                bf16* __restrict__ qT, bf16* __restrict__ kT,
                                                bf16* __restrict__ vTT) {
    const int b = blockIdx.z, y = blockIdx.y, bx = blockIdx.x;
    const int tid = threadIdx.x;
    const int w = tid >> 6, lane = tid & 63, quad = lane >> 4, l15 = lane & 15;
    const int wm = w >> 1, wn = w & 1;
    const size_t bL = (size_t)b * L_DIM;

    f32x4 acc[4][4];
#pragma unroll
    for (int i = 0; i < 4; ++i)
#pragma unroll
        for (int j = 0; j < 4; ++j) acc[i][j] = (f32x4){0.f, 0.f, 0.f, 0.f};

    const bf16* arow[4];
    const bf16* brow[4];
    if (y == 0) {
        const int mbase = bx * 128 + wm * 64;
        const bf16* Wb = wn ? Wkb : Wqb;
#pragma unroll
        for (int mi = 0; mi < 4; ++mi) arow[mi] = xT + (bL + mbase + mi * 16 + l15) * C_DIM;
#pragma unroll
        for (int ni = 0; ni < 4; ++ni) brow[ni] = Wb + (size_t)(ni * 16 + l15) * C_DIM;
    } else {
        const int cbase = (y - 1) * 128 + wm * 64;
        const int lbase = bx * 128 + wn * 64;
#pragma unroll
        for (int mi = 0; mi < 4; ++mi) arow[mi] = Wvb + (size_t)(cbase + mi * 16 + l15) * C_DIM;
#pragma unroll
        for (int ni = 0; ni < 4; ++ni) brow[ni] = xT + (bL + lbase + ni * 16 + l15) * C_DIM;
    }

    bf16x8 af[4], bfr[4], afn[4], bfn[4];
    {
        const int ko = quad * 8;
#pragma unroll
        for (int mi = 0; mi < 4; ++mi) af[mi] = *(const bf16x8*)(arow[mi] + ko);
#pragma unroll
        for (int ni = 0; ni < 4; ++ni) bfr[ni] = *(const bf16x8*)(brow[ni] + ko);
    }
    for (int kt = 0; kt < 16; ++kt) {
        if (kt < 15) {
            const int ko = (kt + 1) * 32 + quad * 8;
#pragma unroll
            for (int mi = 0; mi < 4; ++mi) afn[mi] = *(const bf16x8*)(arow[mi] + ko);
#pragma unroll
            for (int ni = 0; ni < 4; ++ni) bfn[ni] = *(const bf16x8*)(brow[ni] + ko);
        }
#pragma unroll
        for (int mi = 0; mi < 4; ++mi)
#pragma unroll
            for (int ni = 0; ni < 4; ++ni)
                acc[mi][ni] = MFMA16(af[mi], bfr[ni], acc[mi][ni]);
#pragma unroll
        for (int i = 0; i < 4; ++i) { af[i] = afn[i]; bfr[i] = bfn[i]; }
    }

    if (y == 0) {
        const int mbase = bx * 128 + wm * 64;
        const float* bias = wn ? bk : bq;
        bf16* dst = wn ? kT : qT;
        const float sc = wn ? 1.0f : 0.18033688f;   // 0.125 * log2(e)
        float bb[4];
#pragma unroll
        for (int ni = 0; ni < 4; ++ni) bb[ni] = bias[ni * 16 + l15];
#pragma unroll
        for (int mi = 0; mi < 4; ++mi)
#pragma unroll
            for (int r = 0; r < 4; ++r) {
                int l = mbase + mi * 16 + quad * 4 + r;
#pragma unroll
                for (int ni = 0; ni < 4; ++ni)
                    dst[(bL + l) * 64 + ni * 16 + l15] = __float2bfloat16((acc[mi][ni][r] + bb[ni]) * sc);
            }
    } else {
        const int cbase = (y - 1) * 128 + wm * 64;
        const int lbase = bx * 128 + wn * 64;
#pragma unroll
        for (int mi = 0; mi < 4; ++mi)
#pragma unroll
            for (int r = 0; r < 4; ++r) {
                int c = cbase + mi * 16 + quad * 4 + r;
                float bb = bv[c];
#pragma unroll
                for (int ni = 0; ni < 4; ++ni)
                    vTT[((size_t)b * C_DIM + c) * L_DIM + lbase + ni * 16 + l15] =
                        __float2bfloat16(acc[mi][ni][r] + bb);
            }
    }
}

// ---------------- K2: MFMA attention, compile-time interleaved (T19) ----------------
// Round-6: r5's dataflow split nulled because hipcc emitted score-then-PV as
// contiguous blocks -- a wave issues in order, so the tile stayed serial
// (MFMA 930cy + VALU + LDS + stage ~= the observed 3020cy/tile, i.e. fully
// serialized). This round forces the interleave in the EMITTED stream:
// source-interleaved {PV cluster | score pair | exp cluster} with
// sched_group_barrier pins. PV cg0-3 (needs only pre-barrier vBr + paC) leads,
// covering the kf ds_read latency; exp clusters slot into PV MFMA shadows.
// exp2f (Q pre-scaled by log2e/8) replaces expf. Geometry/staging unchanged
// from the r4-verified version (Q=256, c-split 4, grid 256, triple+1-buffered
// LDS, counted vmcnt(2), one barrier/tile).
__global__ __launch_bounds__(512, 2) void k_attn(const bf16* __restrict__ qT,
                                                 const bf16* __restrict__ kT,
                                                 const bf16* __restrict__ vTT,
                                                 bf16* __restrict__ o1) {
    const int bid = blockIdx.x;
    const int b  = bid & 7;
    const int qt = (bid >> 3) & 7;
    const int cs = bid >> 6;                 // 0..3
    const int q0 = qt * 256;
    const int c0 = cs * 128;
    const int tid = threadIdx.x;
    const int w = tid >> 6, lane = tid & 63;
    const int quad = lane >> 4, l15 = lane & 15;

    // V: 4 bufs x 8KB @0 ; K: 4 bufs x 4KB @32768
    __shared__ __align__(16) char lds[49152];

    const size_t bL = (size_t)b * L_DIM;
    const bf16* kb = kT + bL * 64;

    // Q fragments: two 16-row subtiles (q = q0 + w*32 + u*16 + l15), pre-scaled
    bf16x8 qf[2][2];
#pragma unroll
    for (int u = 0; u < 2; ++u) {
        const bf16* qrow = qT + (bL + q0 + w * 32 + u * 16 + l15) * 64;
        qf[u][0] = *(const bf16x8*)(qrow + quad * 8);
        qf[u][1] = *(const bf16x8*)(qrow + 32 + quad * 8);
    }

    f32x4 acc[2][8];
#pragma unroll
    for (int u = 0; u < 2; ++u)
#pragma unroll
        for (int cg = 0; cg < 8; ++cg) acc[u][cg] = (f32x4){0.f, 0.f, 0.f, 0.f};
    float ssum[2] = {0.f, 0.f};

    // hoisted per-lane offsets
    const int vbase = l15 * 64 + ((quad ^ ((l15 >> 1) & 3)) << 4);   // + cg*1024
    const int srcA  = ((quad & 1) * 32 + l15) * 4;

    // cooperative stage of tile kt into buffer bufi (2 loads per thread) -- r4-verified
    auto stage = [&](int kt, int bufi) __attribute__((always_inline)) {
        {   // V tile: 128 c-rows x 64B, layout [c][4x16B], part pre-swizzled
            const int cl = tid >> 2, ps = tid & 3;
            const int pg = ps ^ ((cl >> 1) & 3);
            const bf16* src = vTT + ((size_t)b * C_DIM + c0 + cl) * L_DIM + kt * 32 + pg * 8;
            __builtin_amdgcn_global_load_lds(
                (const __attribute__((address_space(1))) void*)src,
                (__attribute__((address_space(3))) void*)(lds + bufi * 8192 + w * 1024),
                16, 0, 0);
        }
        {   // K tile: 32 k-rows x 128B, layout [k][8x16B]; waves 4-7 duplicate
            const int i = tid & 255, k = i >> 3, sl = i & 7;
            const int sg = sl ^ (k & 7);
            const bf16* src = kb + (size_t)(kt * 32 + k) * 64 + sg * 8;
            __builtin_amdgcn_global_load_lds(
                (const __attribute__((address_space(1))) void*)src,
                (__attribute__((address_space(3))) void*)(lds + 32768 + bufi * 4096 + (w & 3) * 1024),
                16, 0, 0);
        }
    };

    // exp + pack one score group: 4 VALU-min, 4 add, 4 exp2, 4 add, 2 cvt_pk
    auto exppack = [&](const f32x4& s, unsigned& lo, unsigned& hi, float& sm)
        __attribute__((always_inline)) {
        float p0 = exp2f(fminf(s[0], 86.5f) - 5.7707801f);
        float p1 = exp2f(fminf(s[1], 86.5f) - 5.7707801f);
        float p2 = exp2f(fminf(s[2], 86.5f) - 5.7707801f);
        float p3 = exp2f(fminf(s[3], 86.5f) - 5.7707801f);
        sm += (p0 + p1) + (p2 + p3);
        __hip_bfloat162 h01 = __float22bfloat162_rn(make_float2(p0, p1));
        __hip_bfloat162 h23 = __float22bfloat162_rn(make_float2(p2, p3));
        lo = *reinterpret_cast<unsigned*>(&h01);
        hi = *reinterpret_cast<unsigned*>(&h23);
    };

    auto mkpa = [&](unsigned lo0, unsigned hi0, unsigned lo1, unsigned hi1, bf16x8& pa)
        __attribute__((always_inline)) {
        int sel01 = (quad < 2) ? (int)lo0 : (int)lo1;
        int sel23 = (quad < 2) ? (int)hi0 : (int)hi1;
        int a0 = __builtin_amdgcn_ds_bpermute(srcA,      sel01);
        int a1 = __builtin_amdgcn_ds_bpermute(srcA,      sel23);
        int a2 = __builtin_amdgcn_ds_bpermute(srcA + 64, sel01);
        int a3 = __builtin_amdgcn_ds_bpermute(srcA + 64, sel23);
        int4 pi = make_int4(a0, a1, a2, a3);
        pa = *reinterpret_cast<bf16x8*>(&pi);
    };

    bf16x8 paA[2], paB[2];

    // one pipeline step: PV(i-1) from paC/V(i-1) interleaved with score(i)->paN
    auto step = [&](int i, bf16x8 (&paC)[2], bf16x8 (&paN)[2],
                    bool doPV, bool doStage, int vm) __attribute__((always_inline)) -> void {
        // pre-read V(i-1) B-frags BEFORE the sync (buffer valid since barrier i-1;
        // next write to it is stage(i+3), issued after barrier i+1)
        bf16x8 vBr[8];
        if (doPV) {
            char* Vb = lds + ((i - 1) & 3) * 8192;
#pragma unroll
            for (int cg = 0; cg < 8; ++cg)
                vBr[cg] = *(const bf16x8*)(Vb + vbase + cg * 1024);
        }
        if (vm == 0) asm volatile("s_waitcnt vmcnt(0)" ::: "memory");
        else         asm volatile("s_waitcnt vmcnt(2)" ::: "memory");
        __builtin_amdgcn_s_barrier();
        __builtin_amdgcn_sched_barrier(0);
        if (doStage) stage(i + 2, (i + 2) & 3);

        char* Kb = lds + 32768 + (i & 3) * 4096;
        const int krow = l15 * 128, ksw = (l15 & 7);
        bf16x8 kf00 = *(const bf16x8*)(Kb + krow +        (((quad) ^ ksw) << 4));
        bf16x8 kf01 = *(const bf16x8*)(Kb + krow +        (((4 + quad) ^ ksw) << 4));
        bf16x8 kf10 = *(const bf16x8*)(Kb + 2048 + krow + (((quad) ^ ksw) << 4));
        bf16x8 kf11 = *(const bf16x8*)(Kb + 2048 + krow + (((4 + quad) ^ ksw) << 4));
        SGB(0x100, 4, 0);                          // kf ds_reads issue first

        // PV cg0-3: needs only vBr (pre-barrier) + paC -> leads, covers kf latency
        if (doPV) {
            acc[0][0] = MFMA16(paC[0], vBr[0], acc[0][0]);
            acc[1][0] = MFMA16(paC[1], vBr[0], acc[1][0]);
            acc[0][1] = MFMA16(paC[0], vBr[1], acc[0][1]);
            acc[1][1] = MFMA16(paC[1], vBr[1], acc[1][1]);
            acc[0][2] = MFMA16(paC[0], vBr[2], acc[0][2]);
            acc[1][2] = MFMA16(paC[1], vBr[2], acc[1][2]);
            acc[0][3] = MFMA16(paC[0], vBr[3], acc[0][3]);
            acc[1][3] = MFMA16(paC[1], vBr[3], acc[1][3]);
        }
        SGB(0x8, 8, 0);

        f32x4 s0 = (f32x4){0.f, 0.f, 0.f, 0.f};
        s0 = MFMA16(kf00, qf[0][0], s0); s0 = MFMA16(kf01, qf[0][1], s0);
        f32x4 s1 = (f32x4){0.f, 0.f, 0.f, 0.f};
        s1 = MFMA16(kf10, qf[0][0], s1); s1 = MFMA16(kf11, qf[0][1], s1);
        SGB(0x8, 4, 0);

        if (doPV) {
            acc[0][4] = MFMA16(paC[0], vBr[4], acc[0][4]);
            acc[1][4] = MFMA16(paC[1], vBr[4], acc[1][4]);
            acc[0][5] = MFMA16(paC[0], vBr[5], acc[0][5]);
            acc[1][5] = MFMA16(paC[1], vBr[5], acc[1][5]);
        }
        SGB(0x8, 4, 0);

        unsigned h000, h001; exppack(s0, h000, h001, ssum[0]);
        SGB(0x2, 18, 0);

        f32x4 s2 = (f32x4){0.f, 0.f, 0.f, 0.f};
        s2 = MFMA16(kf00, qf[1][0], s2); s2 = MFMA16(kf01, qf[1][1], s2);
        SGB(0x8, 2, 0);

        if (doPV) {
            acc[0][6] = MFMA16(paC[0], vBr[6], acc[0][6]);
            acc[1][6] = MFMA16(paC[1], vBr[6], acc[1][6]);
            acc[0][7] = MFMA16(paC[0], vBr[7], acc[0][7]);
            acc[1][7] = MFMA16(paC[1], vBr[7], acc[1][7]);
        }
        SGB(0x8, 4, 0);

        unsigned h010, h011; exppack(s1, h010, h011, ssum[0]);
        SGB(0x2, 18, 0);

        f32x4 s3 = (f32x4){0.f, 0.f, 0.f, 0.f};
        s3 = MFMA16(kf10, qf[1][0], s3); s3 = MFMA16(kf11, qf[1][1], s3);
        SGB(0x8, 2, 0);

        mkpa(h000, h001, h010, h011, paN[0]);      // pa[0] as soon as u0 done

        unsigned h100, h101; exppack(s2, h100, h101, ssum[1]);
        unsigned h110, h111; exppack(s3, h110, h111, ssum[1]);
        SGB(0x2, 36, 0);

        mkpa(h100, h101, h110, h111, paN[1]);
    };

    stage(0, 0);
    stage(1, 1);
    step(0, paA, paA, false, true, 2);                 // score(0)->paA, stage(2)
    for (int i = 1; i < 63; i += 2) {
        step(i,     paA, paB, true, true,        2);   // PV(i-1), score(i)->paB
        step(i + 1, paB, paA, true, (i + 1) <= 61, 2); // PV(i),   score(i+1)->paA
    }
    step(63, paA, paB, true, false, 0);                // PV(62), score(63)->paB

    // drain: PV(63) from buffer 3
    {
        char* Vb = lds + 3 * 8192;
#pragma unroll
        for (int cg = 0; cg < 8; ++cg) {
            bf16x8 vB = *(const bf16x8*)(Vb + vbase + cg * 1024);
            acc[0][cg] = MFMA16(paB[0], vB, acc[0][cg]);
            acc[1][cg] = MFMA16(paB[1], vB, acc[1][cg]);
        }
    }

    // epilogue: reduce S over quads (q = l15 lane-local), normalize, store
#pragma unroll
    for (int u = 0; u < 2; ++u) {
        ssum[u] += __shfl_xor(ssum[u], 16, 64);
        ssum[u] += __shfl_xor(ssum[u], 32, 64);
        float sinv = 1.f / ssum[u];
#pragma unroll
        for (int r = 0; r < 4; ++r) {
            float iv = __shfl(sinv, quad * 4 + r, 64);
            const size_t base = (bL + q0 + w * 32 + u * 16 + quad * 4 + r) * C_DIM + c0;
#pragma unroll
            for (int cg = 0; cg < 8; ++cg)
                o1[base + cg * 16 + l15] = __float2bfloat16(acc[u][cg][r] * iv);
        }
    }
}

// ---------------- K3: Wo GEMM + bias + residual via MFMA (reg-prefetched) ----------------
__global__ __launch_bounds__(256, 2) void k_out(const float* __restrict__ x,
                                                const bf16* __restrict__ Wob,
                                                const float* __restrict__ bo,
                                                const bf16* __restrict__ o1,
                                                float* __restrict__ out) {
    const int b = blockIdx.z;
    const int tid = threadIdx.x;
    const int w = tid >> 6, lane = tid & 63, quad = lane >> 4, l15 = lane & 15;
    const int wm = w >> 1, wn = w & 1;
    const int mbase = blockIdx.y * 128 + wm * 64;
    const int nbase = blockIdx.x * 128 + wn * 64;
    const size_t bL = (size_t)b * L_DIM;

    f32x4 acc[4][4];
#pragma unroll
    for (int i = 0; i < 4; ++i)
#pragma unroll
        for (int j = 0; j < 4; ++j) acc[i][j] = (f32x4){0.f, 0.f, 0.f, 0.f};

    const bf16* arow[4];
    const bf16* brow[4];
#pragma unroll
    for (int mi = 0; mi < 4; ++mi) arow[mi] = Wob + (size_t)(mbase + mi * 16 + l15) * C_DIM;
#pragma unroll
    for (int ni = 0; ni < 4; ++ni) brow[ni] = o1 + (bL + nbase + ni * 16 + l15) * C_DIM;

    bf16x8 af[4], bfr[4], afn[4], bfn[4];
    {
        const int ko = quad * 8;
#pragma unroll
        for (int mi = 0; mi < 4; ++mi) af[mi] = *(const bf16x8*)(arow[mi] + ko);
#pragma unroll
        for (int ni = 0; ni < 4; ++ni) bfr[ni] = *(const bf16x8*)(brow[ni] + ko);
    }
    for (int kt = 0; kt < 16; ++kt) {
        if (kt < 15) {
            const int ko = (kt + 1) * 32 + quad * 8;
#pragma unroll
            for (int mi = 0; mi < 4; ++mi) afn[mi] = *(const bf16x8*)(arow[mi] + ko);
#pragma unroll
            for (int ni = 0; ni < 4; ++ni) bfn[ni] = *(const bf16x8*)(brow[ni] + ko);
        }
#pragma unroll
        for (int mi = 0; mi < 4; ++mi)
#pragma unroll
            for (int ni = 0; ni < 4; ++ni)
                acc[mi][ni] = MFMA16(af[mi], bfr[ni], acc[mi][ni]);
#pragma unroll
        for (int i = 0; i < 4; ++i) { af[i] = afn[i]; bfr[i] = bfn[i]; }
    }

#pragma unroll
    for (int mi = 0; mi < 4; ++mi)
#pragma unroll
        for (int r = 0; r < 4; ++r) {
            int row = mbase + mi * 16 + quad * 4 + r;
            float bb = bo[row];
            size_t base = ((size_t)b * C_DIM + row) * L_DIM + nbase;
#pragma unroll
            for (int ni = 0; ni < 4; ++ni) {
                size_t idx = base + ni * 16 + l15;
                out[idx] = acc[mi][ni][r] + bb + x[idx];
            }
        }
}

extern "C" void kernel_launch(void* const* d_in, const int* in_sizes, int n_in,
                              void* d_out, int out_size, void* d_ws, size_t ws_size,
                              hipStream_t stream) {
    const float* x  = (const float*)d_in[0];
    const float* Wq = (const float*)d_in[1];
    const float* bq = (const float*)d_in[2];
    const float* Wk = (const float*)d_in[3];
    const float* bk = (const float*)d_in[4];
    const float* Wv = (const float*)d_in[5];
    const float* bv = (const float*)d_in[6];
    const float* Wo = (const float*)d_in[7];
    const float* bo = (const float*)d_in[8];

    char* wsb = (char*)d_ws;
    bf16* xT  = (bf16*)(wsb + OFF_XT);
    bf16* Wqb = (bf16*)(wsb + OFF_WQB);
    bf16* Wkb = (bf16*)(wsb + OFF_WKB);
    bf16* Wvb = (bf16*)(wsb + OFF_WVB);
    bf16* Wob = (bf16*)(wsb + OFF_WOB);
    bf16* qT  = (bf16*)(wsb + OFF_QT);
    bf16* kT  = (bf16*)(wsb + OFF_KT);
    bf16* vTT = (bf16*)(wsb + OFF_VT);
    bf16* o1  = (bf16*)(wsb + OFF_O1);
    float* out = (float*)d_out;

    k_wcvt<<<dim3(2304), 256, 0, stream>>>(Wq, Wk, Wv, Wo, Wqb, Wkb, Wvb, Wob);
    k_tr<<<dim3(L_DIM / 64, C_DIM / 64, B_DIM), 256, 0, stream>>>(x, xT);
    k_qkv<<<dim3(16, 5, B_DIM), 256, 0, stream>>>(xT, Wqb, bq, Wkb, bk, Wvb, bv, qT, kT, vTT);
    k_attn<<<dim3(256), 512, 0, stream>>>(qT, kT, vTT, o1);
    k_out<<<dim3(16, 4, B_DIM), 256, 0, stream>>>(x, Wob, bo, o1, out);
}